// Round 1
// baseline (296.002 us; speedup 1.0000x reference)
//
#include <hip/hip_runtime.h>
#include <stdint.h>

typedef __bf16 bf16x8 __attribute__((ext_vector_type(8)));
typedef float  f32x4  __attribute__((ext_vector_type(4)));
typedef float  float4v __attribute__((ext_vector_type(4)));
typedef short  short8 __attribute__((ext_vector_type(8)));
typedef short  short4v __attribute__((ext_vector_type(4)));

static constexpr int Bb = 4, Ss = 2048;
static constexpr int Mtot = Bb * Ss;     // 8192
static constexpr int Ntot = 2048;        // D_OUT
static constexpr int Ktot = 2048;        // D_IN
static constexpr int NE = 8, NR = 16;
static constexpr float SCALING = 16.0f / 16.0f;

__device__ __forceinline__ ushort f2bf(float f) {
  union { float f; uint32_t u; } v; v.f = f;
  uint32_t r = (v.u + 0x7FFFu + ((v.u >> 16) & 1u)) >> 16;
  return (ushort)r;
}

__device__ __forceinline__ void lds16(const void* g, void* l) {
  __builtin_amdgcn_global_load_lds(
      (const __attribute__((address_space(1))) void*)g,
      (__attribute__((address_space(3))) void*)l, 16, 0, 0);
}

// ---------- kernel 1: x fp32 -> bf16 (vectorized) ----------
__global__ __launch_bounds__(256) void k_cvt_x(const float* __restrict__ x,
                                               ushort* __restrict__ xb) {
  size_t i = ((size_t)blockIdx.x * 256 + threadIdx.x) * 8;
  float4v a = *reinterpret_cast<const float4v*>(x + i);
  float4v c = *reinterpret_cast<const float4v*>(x + i + 4);
  short8 o;
  o[0] = (short)f2bf(a[0]); o[1] = (short)f2bf(a[1]);
  o[2] = (short)f2bf(a[2]); o[3] = (short)f2bf(a[3]);
  o[4] = (short)f2bf(c[0]); o[5] = (short)f2bf(c[1]);
  o[6] = (short)f2bf(c[2]); o[7] = (short)f2bf(c[3]);
  *reinterpret_cast<short8*>(xb + i) = o;
}

// ---------- kernel 2: W_eff = W + SCALING * sum_e m_e * B_e @ A_e  -> bf16 ----------
__global__ __launch_bounds__(256) void k_weff(const float* __restrict__ W,
                                              const float* __restrict__ lA,   // [E][R][K]
                                              const float* __restrict__ lB,   // [E][N][R]
                                              const int* __restrict__ mask,   // [E]
                                              ushort* __restrict__ Wb) {
  __shared__ float bv[NE * NR];
  int o = blockIdx.x;
  int tid = threadIdx.x;
  if (tid < NE * NR) {
    int e = tid >> 4, r = tid & 15;
    float m = (mask[e] != 0) ? SCALING : 0.0f;
    bv[tid] = lB[((size_t)e * Ntot + o) * NR + r] * m;
  }
  __syncthreads();
  #pragma unroll
  for (int pass = 0; pass < 2; ++pass) {
    int d = (pass * 256 + tid) * 4;
    float4v acc = *reinterpret_cast<const float4v*>(W + (size_t)o * Ktot + d);
    #pragma unroll
    for (int e = 0; e < NE; ++e) {
      #pragma unroll
      for (int r = 0; r < NR; ++r) {
        float bw = bv[e * NR + r];
        float4v av = *reinterpret_cast<const float4v*>(lA + (size_t)(e * NR + r) * Ktot + d);
        acc[0] += bw * av[0]; acc[1] += bw * av[1];
        acc[2] += bw * av[2]; acc[3] += bw * av[3];
      }
    }
    short4v s;
    s[0] = (short)f2bf(acc[0]); s[1] = (short)f2bf(acc[1]);
    s[2] = (short)f2bf(acc[2]); s[3] = (short)f2bf(acc[3]);
    *reinterpret_cast<short4v*>(Wb + (size_t)o * Ktot + d) = s;
  }
}

// ---------- kernel 3: out[M][N] = Xb[M][K] @ Wb[N][K]^T + bias ----------
// m97 structure: 128x128 tile, BK=32, 4 waves (2x2), 4x4 16x16x32 frags/wave,
// global_load_lds width-16 staging, 2-barrier K loop.
__global__ __launch_bounds__(256) void k_gemm(const ushort* __restrict__ Xb,
                                              const ushort* __restrict__ Wb,
                                              const float* __restrict__ bias,
                                              float* __restrict__ out) {
  constexpr int BM = 128, BN = 128, BK = 32;
  constexpr int NTN = Ntot / BN;  // 16
  __shared__ __align__(16) ushort As[BM * BK];
  __shared__ __align__(16) ushort Bs[BN * BK];

  // bijective XCD swizzle (nwg % 8 == 0)
  int nwg = gridDim.x;
  int orig = blockIdx.x;
  int wg = (orig & 7) * (nwg >> 3) + (orig >> 3);
  int mBase = (wg / NTN) * BM;
  int nBase = (wg % NTN) * BN;

  int tid = threadIdx.x;
  int w = tid >> 6, l = tid & 63;

  // staging: wave w, inst j in {0,1}: lane l covers LDS bytes w*2048+j*1024+l*16
  // -> tile row = w*32 + j*16 + (l>>2), k-elt = (l&3)*8
  int stRow = w * 32 + (l >> 2);
  int stCol = (l & 3) * 8;
  const ushort* gA0 = Xb + (size_t)(mBase + stRow) * Ktot + stCol;
  const ushort* gB0 = Wb + (size_t)(nBase + stRow) * Ktot + stCol;
  ushort* lA0 = As + w * 1024;   // wave-uniform LDS bases (elements)
  ushort* lB0 = Bs + w * 1024;

  f32x4 acc[4][4];
  #pragma unroll
  for (int i = 0; i < 4; ++i)
    #pragma unroll
    for (int j = 0; j < 4; ++j) acc[i][j] = f32x4{0.f, 0.f, 0.f, 0.f};

  int wm = (w >> 1) * 64, wn = (w & 1) * 64;
  int fr = l & 15;          // fragment row (A) / col (B)
  int fk = (l >> 4) * 8;    // k offset within BK

  const ushort* raBase = As + (wm + fr) * BK + fk;
  const ushort* rbBase = Bs + (wn + fr) * BK + fk;

  for (int kt = 0; kt < Ktot; kt += BK) {
    lds16(gA0 + kt, lA0);
    lds16(gA0 + kt + 16 * Ktot, lA0 + 512);
    lds16(gB0 + kt, lB0);
    lds16(gB0 + kt + 16 * Ktot, lB0 + 512);
    __syncthreads();   // drains vmcnt before barrier -> LDS ready

    bf16x8 af[4], bg[4];
    #pragma unroll
    for (int i = 0; i < 4; ++i) {
      af[i] = *reinterpret_cast<const bf16x8*>(raBase + i * 16 * BK);
      bg[i] = *reinterpret_cast<const bf16x8*>(rbBase + i * 16 * BK);
    }
    #pragma unroll
    for (int i = 0; i < 4; ++i)
      #pragma unroll
      for (int j = 0; j < 4; ++j)
        acc[i][j] = __builtin_amdgcn_mfma_f32_16x16x32_bf16(af[i], bg[j], acc[i][j], 0, 0, 0);
    __syncthreads();   // protect LDS before next stage
  }

  // epilogue: C/D map col=lane&15, row=(lane>>4)*4+reg
  int rr = (l >> 4) * 4;
  #pragma unroll
  for (int j = 0; j < 4; ++j) {
    int col = nBase + wn + j * 16 + fr;
    float bb = bias[col];
    #pragma unroll
    for (int i = 0; i < 4; ++i) {
      int row0 = mBase + wm + i * 16 + rr;
      #pragma unroll
      for (int r = 0; r < 4; ++r)
        out[(size_t)(row0 + r) * Ntot + col] = acc[i][j][r] + bb;
    }
  }
}

extern "C" void kernel_launch(void* const* d_in, const int* in_sizes, int n_in,
                              void* d_out, int out_size, void* d_ws, size_t ws_size,
                              hipStream_t stream) {
  const float* x    = (const float*)d_in[0];
  const float* W    = (const float*)d_in[1];
  const float* bias = (const float*)d_in[2];
  const float* lA   = (const float*)d_in[3];
  const float* lB   = (const float*)d_in[4];
  const int*   mask = (const int*)d_in[5];
  float* out = (float*)d_out;

  ushort* xb = (ushort*)d_ws;                       // [M][K] bf16: 33.5 MB
  ushort* wb = xb + (size_t)Mtot * Ktot;            // [N][K] bf16:  8.4 MB

  k_cvt_x<<<(Mtot * Ktot) / (256 * 8), 256, 0, stream>>>(x, xb);
  k_weff<<<Ntot, 256, 0, stream>>>(W, lA, lB, mask, wb);
  k_gemm<<<(Mtot / 128) * (Ntot / 128), 256, 0, stream>>>(xb, wb, bias, out);
}

// Round 2
// 290.121 us; speedup vs baseline: 1.0203x; 1.0203x over previous
//
#include <hip/hip_runtime.h>
#include <stdint.h>

typedef __bf16 bf16x8 __attribute__((ext_vector_type(8)));
typedef float  f32x4  __attribute__((ext_vector_type(4)));
typedef float  float4v __attribute__((ext_vector_type(4)));
typedef short  short8 __attribute__((ext_vector_type(8)));
typedef short  short4v __attribute__((ext_vector_type(4)));

static constexpr int Bb = 4, Ss = 2048;
static constexpr int Mtot = Bb * Ss;     // 8192
static constexpr int Ntot = 2048;        // D_OUT
static constexpr int Ktot = 2048;        // D_IN
static constexpr int NE = 8, NR = 16;
static constexpr int ERTOT = NE * NR;    // 128
static constexpr float SCALING = 16.0f / 16.0f;

__device__ __forceinline__ ushort f2bf(float f) {
  union { float f; uint32_t u; } v; v.f = f;
  uint32_t r = (v.u + 0x7FFFu + ((v.u >> 16) & 1u)) >> 16;
  return (ushort)r;
}

__device__ __forceinline__ void lds16(const void* g, void* l) {
  __builtin_amdgcn_global_load_lds(
      (const __attribute__((address_space(1))) void*)g,
      (__attribute__((address_space(3))) void*)l, 16, 0, 0);
}

// ---------- kernel 1: x fp32 -> bf16 (vectorized) ----------
__global__ __launch_bounds__(256) void k_cvt_x(const float* __restrict__ x,
                                               ushort* __restrict__ xb) {
  size_t i = ((size_t)blockIdx.x * 256 + threadIdx.x) * 8;
  float4v a = *reinterpret_cast<const float4v*>(x + i);
  float4v c = *reinterpret_cast<const float4v*>(x + i + 4);
  short8 o;
  o[0] = (short)f2bf(a[0]); o[1] = (short)f2bf(a[1]);
  o[2] = (short)f2bf(a[2]); o[3] = (short)f2bf(a[3]);
  o[4] = (short)f2bf(c[0]); o[5] = (short)f2bf(c[1]);
  o[6] = (short)f2bf(c[2]); o[7] = (short)f2bf(c[3]);
  *reinterpret_cast<short8*>(xb + i) = o;
}

// ---------- kernel 2: W_eff = W + SCALING * sum_e m_e * B_e @ A_e  -> bf16 ----------
// Tiled rank-128 update: block = [16 N-rows][64 K-cols] tile, 256 threads
// (tx=16 col-groups of float4, ty=16 rows). lB slice staged in LDS (stride
// 129 to avoid 4-way bank conflict on the broadcast read); lA streamed
// coalesced with 16-row reuse. lA traffic: 4096 blocks * 32KB = 128MB (L2).
__global__ __launch_bounds__(256) void k_weff(const float* __restrict__ W,
                                              const float* __restrict__ lA,   // [E][R][K]
                                              const float* __restrict__ lB,   // [E][N][R]
                                              const int* __restrict__ mask,   // [E]
                                              ushort* __restrict__ Wb) {
  __shared__ float bv[16][ERTOT + 1];   // +1 pad: banks differ across rows
  int bid = blockIdx.x;
  int o0 = (bid & 127) * 16;            // N-tile  (2048/16 = 128)
  int d0 = (bid >> 7) * 64;             // K-tile  (2048/64 = 32)
  int tid = threadIdx.x;

  for (int t = tid; t < 16 * ERTOT; t += 256) {
    int r = t >> 7;          // local row 0..15
    int i = t & 127;         // inner   0..127
    int e = i >> 4, rr = i & 15;
    float m = (mask[e] != 0) ? SCALING : 0.0f;
    bv[r][i] = lB[((size_t)e * Ntot + (o0 + r)) * NR + rr] * m;
  }
  __syncthreads();

  int tx = tid & 15, ty = tid >> 4;
  int d = d0 + tx * 4;
  int o = o0 + ty;
  float4v acc = *reinterpret_cast<const float4v*>(W + (size_t)o * Ktot + d);
  #pragma unroll 4
  for (int i = 0; i < ERTOT; ++i) {
    float bw = bv[ty][i];
    float4v av = *reinterpret_cast<const float4v*>(lA + (size_t)i * Ktot + d);
    acc[0] += bw * av[0]; acc[1] += bw * av[1];
    acc[2] += bw * av[2]; acc[3] += bw * av[3];
  }
  short4v s;
  s[0] = (short)f2bf(acc[0]); s[1] = (short)f2bf(acc[1]);
  s[2] = (short)f2bf(acc[2]); s[3] = (short)f2bf(acc[3]);
  *reinterpret_cast<short4v*>(Wb + (size_t)o * Ktot + d) = s;
}

// ---------- kernel 3: out[M][N] = Xb[M][K] @ Wb[N][K]^T + bias ----------
// m97 structure: 128x128 tile, BK=32, 4 waves (2x2), 4x4 16x16x32 frags/wave,
// global_load_lds width-16 staging, 2-barrier K loop.
__global__ __launch_bounds__(256) void k_gemm(const ushort* __restrict__ Xb,
                                              const ushort* __restrict__ Wb,
                                              const float* __restrict__ bias,
                                              float* __restrict__ out) {
  constexpr int BM = 128, BN = 128, BK = 32;
  constexpr int NTN = Ntot / BN;  // 16
  __shared__ __align__(16) ushort As[BM * BK];
  __shared__ __align__(16) ushort Bs[BN * BK];

  // bijective XCD swizzle (nwg % 8 == 0)
  int nwg = gridDim.x;
  int orig = blockIdx.x;
  int wg = (orig & 7) * (nwg >> 3) + (orig >> 3);
  int mBase = (wg / NTN) * BM;
  int nBase = (wg % NTN) * BN;

  int tid = threadIdx.x;
  int w = tid >> 6, l = tid & 63;

  // staging: wave w, inst j in {0,1}: lane l covers LDS bytes w*2048+j*1024+l*16
  // -> tile row = w*32 + j*16 + (l>>2), k-elt = (l&3)*8
  int stRow = w * 32 + (l >> 2);
  int stCol = (l & 3) * 8;
  const ushort* gA0 = Xb + (size_t)(mBase + stRow) * Ktot + stCol;
  const ushort* gB0 = Wb + (size_t)(nBase + stRow) * Ktot + stCol;
  ushort* lA0 = As + w * 1024;   // wave-uniform LDS bases (elements)
  ushort* lB0 = Bs + w * 1024;

  f32x4 acc[4][4];
  #pragma unroll
  for (int i = 0; i < 4; ++i)
    #pragma unroll
    for (int j = 0; j < 4; ++j) acc[i][j] = f32x4{0.f, 0.f, 0.f, 0.f};

  int wm = (w >> 1) * 64, wn = (w & 1) * 64;
  int fr = l & 15;          // fragment row (A) / col (B)
  int fk = (l >> 4) * 8;    // k offset within BK

  const ushort* raBase = As + (wm + fr) * BK + fk;
  const ushort* rbBase = Bs + (wn + fr) * BK + fk;

  for (int kt = 0; kt < Ktot; kt += BK) {
    lds16(gA0 + kt, lA0);
    lds16(gA0 + kt + 16 * Ktot, lA0 + 512);
    lds16(gB0 + kt, lB0);
    lds16(gB0 + kt + 16 * Ktot, lB0 + 512);
    __syncthreads();   // drains vmcnt before barrier -> LDS ready

    bf16x8 af[4], bg[4];
    #pragma unroll
    for (int i = 0; i < 4; ++i) {
      af[i] = *reinterpret_cast<const bf16x8*>(raBase + i * 16 * BK);
      bg[i] = *reinterpret_cast<const bf16x8*>(rbBase + i * 16 * BK);
    }
    #pragma unroll
    for (int i = 0; i < 4; ++i)
      #pragma unroll
      for (int j = 0; j < 4; ++j)
        acc[i][j] = __builtin_amdgcn_mfma_f32_16x16x32_bf16(af[i], bg[j], acc[i][j], 0, 0, 0);
    __syncthreads();   // protect LDS before next stage
  }

  // epilogue: C/D map col=lane&15, row=(lane>>4)*4+reg
  int rr = (l >> 4) * 4;
  #pragma unroll
  for (int j = 0; j < 4; ++j) {
    int col = nBase + wn + j * 16 + fr;
    float bb = bias[col];
    #pragma unroll
    for (int i = 0; i < 4; ++i) {
      int row0 = mBase + wm + i * 16 + rr;
      #pragma unroll
      for (int r = 0; r < 4; ++r)
        out[(size_t)(row0 + r) * Ntot + col] = acc[i][j][r] + bb;
    }
  }
}

extern "C" void kernel_launch(void* const* d_in, const int* in_sizes, int n_in,
                              void* d_out, int out_size, void* d_ws, size_t ws_size,
                              hipStream_t stream) {
  const float* x    = (const float*)d_in[0];
  const float* W    = (const float*)d_in[1];
  const float* bias = (const float*)d_in[2];
  const float* lA   = (const float*)d_in[3];
  const float* lB   = (const float*)d_in[4];
  const int*   mask = (const int*)d_in[5];
  float* out = (float*)d_out;

  ushort* xb = (ushort*)d_ws;                       // [M][K] bf16: 33.5 MB
  ushort* wb = xb + (size_t)Mtot * Ktot;            // [N][K] bf16:  8.4 MB

  k_cvt_x<<<(Mtot * Ktot) / (256 * 8), 256, 0, stream>>>(x, xb);
  k_weff<<<(Ntot / 16) * (Ktot / 64), 256, 0, stream>>>(W, lA, lB, mask, wb);
  k_gemm<<<(Mtot / 128) * (Ntot / 128), 256, 0, stream>>>(xb, wb, bias, out);
}

// Round 4
// 258.357 us; speedup vs baseline: 1.1457x; 1.1229x over previous
//
#include <hip/hip_runtime.h>
#include <stdint.h>

typedef __bf16 bf16x8 __attribute__((ext_vector_type(8)));
typedef float  f32x4  __attribute__((ext_vector_type(4)));
typedef float  float4v __attribute__((ext_vector_type(4)));
typedef short  short8 __attribute__((ext_vector_type(8)));
typedef short  short4v __attribute__((ext_vector_type(4)));

static constexpr int Mtot = 8192;        // B*S
static constexpr int Ntot = 2048;        // D_OUT
static constexpr int Ktot = 2048;        // D_IN
static constexpr int NE = 8, NR = 16;
static constexpr int ERTOT = NE * NR;    // 128
static constexpr float SCALING = 16.0f / 16.0f;

__device__ __forceinline__ ushort f2bf(float f) {
  union { float f; uint32_t u; } v; v.f = f;
  uint32_t r = (v.u + 0x7FFFu + ((v.u >> 16) & 1u)) >> 16;
  return (ushort)r;
}

__device__ __forceinline__ void lds16(const void* g, void* l) {
  __builtin_amdgcn_global_load_lds(
      (const __attribute__((address_space(1))) void*)g,
      (__attribute__((address_space(3))) void*)l, 16, 0, 0);
}

// ---------- kernel 1: fused {x fp32->bf16} + {W_eff build} ----------
// blocks [0,8192): cvt;  blocks [8192,12288): weff 16x64 tiles.
__global__ __launch_bounds__(256) void k_prep(const float* __restrict__ x,
                                              ushort* __restrict__ xb,
                                              const float* __restrict__ W,
                                              const float* __restrict__ lA,   // [E][R][K]
                                              const float* __restrict__ lB,   // [E][N][R]
                                              const int* __restrict__ mask,   // [E]
                                              ushort* __restrict__ Wb) {
  __shared__ float bv[16][ERTOT + 1];
  int tid = threadIdx.x;
  if (blockIdx.x < 8192) {
    size_t i = ((size_t)blockIdx.x * 256 + tid) * 8;
    float4v a = *reinterpret_cast<const float4v*>(x + i);
    float4v c = *reinterpret_cast<const float4v*>(x + i + 4);
    short8 o;
    o[0] = (short)f2bf(a[0]); o[1] = (short)f2bf(a[1]);
    o[2] = (short)f2bf(a[2]); o[3] = (short)f2bf(a[3]);
    o[4] = (short)f2bf(c[0]); o[5] = (short)f2bf(c[1]);
    o[6] = (short)f2bf(c[2]); o[7] = (short)f2bf(c[3]);
    *reinterpret_cast<short8*>(xb + i) = o;
  } else {
    int bid = blockIdx.x - 8192;
    int o0 = (bid & 127) * 16;            // N-tile
    int d0 = (bid >> 7) * 64;             // K-tile
    for (int t = tid; t < 16 * ERTOT; t += 256) {
      int r = t >> 7, i = t & 127;
      int e = i >> 4, rr = i & 15;
      float m = (mask[e] != 0) ? SCALING : 0.0f;
      bv[r][i] = lB[((size_t)e * Ntot + (o0 + r)) * NR + rr] * m;
    }
    __syncthreads();
    int tx = tid & 15, ty = tid >> 4;
    int d = d0 + tx * 4;
    int o = o0 + ty;
    float4v acc = *reinterpret_cast<const float4v*>(W + (size_t)o * Ktot + d);
    #pragma unroll 4
    for (int i = 0; i < ERTOT; ++i) {
      float bw = bv[ty][i];
      float4v av = *reinterpret_cast<const float4v*>(lA + (size_t)i * Ktot + d);
      acc[0] += bw * av[0]; acc[1] += bw * av[1];
      acc[2] += bw * av[2]; acc[3] += bw * av[3];
    }
    short4v s;
    s[0] = (short)f2bf(acc[0]); s[1] = (short)f2bf(acc[1]);
    s[2] = (short)f2bf(acc[2]); s[3] = (short)f2bf(acc[3]);
    *reinterpret_cast<short4v*>(Wb + (size_t)o * Ktot + d) = s;
  }
}

// ---------- kernel 2: 256x256-tile 8-wave GEMM, counted-vmcnt ring pipeline ----------
// out[M][N] = Xb[M][K] @ Wb[N][K]^T + bias.
// T1 XCD swizzle, T2 XOR swizzle (both-sides), T3+T4 ring of 4 K-tile buffers
// with s_waitcnt vmcnt(4) (never 0 in steady state), T5 setprio around MFMA.
__global__ __launch_bounds__(512, 2) void k_gemm256(const ushort* __restrict__ Xb,
                                                    const ushort* __restrict__ Wb,
                                                    const float* __restrict__ bias,
                                                    float* __restrict__ out) {
  constexpr int BK = 32;
  constexpr int NT = Ktot / BK;           // 64
  constexpr int NTN = Ntot / 256;         // 8
  __shared__ __align__(128) char smem[4 * 32768];   // ring: 4 x (A 16KB + B 16KB)

  int nwg = gridDim.x;                    // 256, %8==0
  int orig = blockIdx.x;
  int wg = (orig & 7) * (nwg >> 3) + (orig >> 3);
  int mBase = (wg / NTN) * 256;
  int nBase = (wg % NTN) * 256;

  int tid = threadIdx.x;
  int w = tid >> 6, l = tid & 63;
  int wr = w >> 2, wc = w & 3;            // wave -> 128x64 output sub-tile

  // ---- staging addressing (one issue = 8KB = 128 rows x 64B) ----
  // thread tid covers LDS byte tid*16 of the issue: row=tid>>2, colbyte=(tid&3)*16.
  // T2: source col XOR'd so linear LDS holds swizzled data (rule #21).
  int rowOff = tid >> 2;
  int cbS = ((tid & 3) * 16) ^ (((tid >> 3) & 3) << 4);
  const char* xbB = (const char*)Xb;
  const char* wbB = (const char*)Wb;
  const char* src[4];
  src[0] = xbB + (size_t)(mBase +       rowOff) * (Ktot * 2) + cbS;  // A rows 0-127
  src[1] = xbB + (size_t)(mBase + 128 + rowOff) * (Ktot * 2) + cbS;  // A rows 128-255
  src[2] = wbB + (size_t)(nBase +       rowOff) * (Ktot * 2) + cbS;  // B rows 0-127
  src[3] = wbB + (size_t)(nBase + 128 + rowOff) * (Ktot * 2) + cbS;  // B rows 128-255
  int waveB = w * 1024;                   // wave-uniform chunk within an issue

  auto stage = [&](int bufn, int which, size_t kb) {
    lds16(src[which] + kb, smem + bufn * 32768 + which * 8192 + waveB);
  };

  // ---- fragment read addressing (same XOR on the read side) ----
  int fr = l & 15;
  int fkb = (l >> 4) * 16;
  int kx = fkb ^ (((fr >> 1) & 3) << 4);
  int aRd = (wr * 128 + fr) * 64 + kx;            // + mi*1024
  int bRd = 16384 + (wc * 64 + fr) * 64 + kx;     // + nj*1024

  f32x4 acc[8][4];
  #pragma unroll
  for (int i = 0; i < 8; ++i)
    #pragma unroll
    for (int j = 0; j < 4; ++j) acc[i][j] = f32x4{0.f, 0.f, 0.f, 0.f};

  bf16x8 aF[4], bF[4];

  // prologue: stage tiles 0 and 1, drain fully once.
  #pragma unroll
  for (int q = 0; q < 4; ++q) stage(0, q, 0);
  #pragma unroll
  for (int q = 0; q < 4; ++q) stage(1, q, 64);
  __syncthreads();

  for (int t = 0; t < NT; ++t) {
    const char* buf = smem + (t & 3) * 32768;
    const bool pref = (t + 2 < NT);
    const int bn = (t + 2) & 3;
    const size_t kb = (size_t)(t + 2) * 64;

    // ---- phase 0: quadrant mh=0 ----
    #pragma unroll
    for (int mi = 0; mi < 4; ++mi)
      aF[mi] = *reinterpret_cast<const bf16x8*>(buf + aRd + mi * 1024);
    #pragma unroll
    for (int nj = 0; nj < 4; ++nj)
      bF[nj] = *reinterpret_cast<const bf16x8*>(buf + bRd + nj * 1024);
    if (pref) { stage(bn, 0, kb); stage(bn, 1, kb); }
    __builtin_amdgcn_s_barrier();
    __builtin_amdgcn_s_setprio(1);
    #pragma unroll
    for (int mi = 0; mi < 4; ++mi)
      #pragma unroll
      for (int nj = 0; nj < 4; ++nj)
        acc[mi][nj] = __builtin_amdgcn_mfma_f32_16x16x32_bf16(aF[mi], bF[nj], acc[mi][nj], 0, 0, 0);
    __builtin_amdgcn_s_setprio(0);
    __builtin_amdgcn_s_barrier();

    // ---- phase 1: quadrant mh=1 (B frags reused) ----
    #pragma unroll
    for (int mi = 0; mi < 4; ++mi)
      aF[mi] = *reinterpret_cast<const bf16x8*>(buf + aRd + (4 + mi) * 1024);
    if (pref) { stage(bn, 2, kb); stage(bn, 3, kb); }
    __builtin_amdgcn_s_barrier();
    __builtin_amdgcn_s_setprio(1);
    #pragma unroll
    for (int mi = 0; mi < 4; ++mi)
      #pragma unroll
      for (int nj = 0; nj < 4; ++nj)
        acc[4 + mi][nj] = __builtin_amdgcn_mfma_f32_16x16x32_bf16(aF[mi], bF[nj], acc[4 + mi][nj], 0, 0, 0);
    __builtin_amdgcn_s_setprio(0);

    // ---- tile boundary: counted vmcnt (T4), then barrier ----
    if (t + 2 < NT)      asm volatile("s_waitcnt vmcnt(4)" ::: "memory");
    else if (t + 1 < NT) asm volatile("s_waitcnt vmcnt(0)" ::: "memory");
    __builtin_amdgcn_s_barrier();
  }

  // ---- epilogue: C/D map col=lane&15, row=(lane>>4)*4+reg ----
  int rr = (l >> 4) * 4;
  #pragma unroll
  for (int nj = 0; nj < 4; ++nj) {
    int col = nBase + wc * 64 + nj * 16 + fr;
    float bb = bias[col];
    #pragma unroll
    for (int mi = 0; mi < 8; ++mi) {
      int row0 = mBase + wr * 128 + mi * 16 + rr;
      #pragma unroll
      for (int r = 0; r < 4; ++r)
        out[(size_t)(row0 + r) * Ntot + col] = acc[mi][nj][r] + bb;
    }
  }
}

extern "C" void kernel_launch(void* const* d_in, const int* in_sizes, int n_in,
                              void* d_out, int out_size, void* d_ws, size_t ws_size,
                              hipStream_t stream) {
  const float* x    = (const float*)d_in[0];
  const float* W    = (const float*)d_in[1];
  const float* bias = (const float*)d_in[2];
  const float* lA   = (const float*)d_in[3];
  const float* lB   = (const float*)d_in[4];
  const int*   mask = (const int*)d_in[5];
  float* out = (float*)d_out;

  ushort* xb = (ushort*)d_ws;                       // [M][K] bf16: 33.5 MB
  ushort* wb = xb + (size_t)Mtot * Ktot;            // [N][K] bf16:  8.4 MB

  k_prep<<<8192 + 4096, 256, 0, stream>>>(x, xb, W, lA, lB, mask, wb);
  k_gemm256<<<(Mtot / 256) * (Ntot / 256), 512, 0, stream>>>(xb, wb, bias, out);
}

// Round 5
// 213.286 us; speedup vs baseline: 1.3878x; 1.2113x over previous
//
#include <hip/hip_runtime.h>
#include <stdint.h>

typedef __bf16 bf16x8 __attribute__((ext_vector_type(8)));
typedef float  f32x4  __attribute__((ext_vector_type(4)));
typedef float  float4v __attribute__((ext_vector_type(4)));
typedef short  short8 __attribute__((ext_vector_type(8)));
typedef short  short4v __attribute__((ext_vector_type(4)));

static constexpr int Mtot = 8192;        // B*S
static constexpr int Ntot = 2048;        // D_OUT
static constexpr int Ktot = 2048;        // D_IN
static constexpr int NE = 8, NR = 16;
static constexpr int R2 = NE * NR;       // 128 stacked rank
static constexpr float SCALING = 16.0f / 16.0f;

__device__ __forceinline__ ushort f2bf(float f) {
  union { float f; uint32_t u; } v; v.f = f;
  uint32_t r = (v.u + 0x7FFFu + ((v.u >> 16) & 1u)) >> 16;
  return (ushort)r;
}

__device__ __forceinline__ void lds16(const void* g, void* l) {
  __builtin_amdgcn_global_load_lds(
      (const __attribute__((address_space(1))) void*)g,
      (__attribute__((address_space(3))) void*)l, 16, 0, 0);
}

// ---------- kernel 1: cvt x -> bf16 (dense) + build Abt/Bst bf16 ----------
// blocks [0,8192): cvt x.  [8192,8200): Abt[d][i]=bf16(lA[i][d]).
// [8200,8208): Bst[o][e*16+r]=bf16(lB[e][o][r]*mask_e*SCALING).
__global__ __launch_bounds__(256) void k_prep(const float* __restrict__ x,
                                              ushort* __restrict__ xb,
                                              const float* __restrict__ lA,   // [E][R][K] = [128][2048]
                                              const float* __restrict__ lB,   // [E][N][R]
                                              const int* __restrict__ mask,   // [E]
                                              ushort* __restrict__ Abt,       // [2048][128]
                                              ushort* __restrict__ Bst) {     // [2048][128]
  int tid = threadIdx.x;
  if (blockIdx.x < 8192) {
    size_t base = (size_t)blockIdx.x * 2048;
    int t4 = tid * 4;
    float4v a = *reinterpret_cast<const float4v*>(x + base + t4);
    float4v c = *reinterpret_cast<const float4v*>(x + base + 1024 + t4);
    short4v s0, s1;
    s0[0] = (short)f2bf(a[0]); s0[1] = (short)f2bf(a[1]);
    s0[2] = (short)f2bf(a[2]); s0[3] = (short)f2bf(a[3]);
    s1[0] = (short)f2bf(c[0]); s1[1] = (short)f2bf(c[1]);
    s1[2] = (short)f2bf(c[2]); s1[3] = (short)f2bf(c[3]);
    *reinterpret_cast<short4v*>(xb + base + t4) = s0;
    *reinterpret_cast<short4v*>(xb + base + 1024 + t4) = s1;
  } else if (blockIdx.x < 8200) {
    // Abt: thread owns column d of lA; reads are wave-coalesced per i.
    int d = (blockIdx.x - 8192) * 256 + tid;
    short8 buf[16];
    #pragma unroll 8
    for (int i = 0; i < R2; ++i)
      ((short*)buf)[i] = (short)f2bf(lA[(size_t)i * Ktot + d]);
    #pragma unroll
    for (int q = 0; q < 16; ++q)
      *reinterpret_cast<short8*>(Abt + (size_t)d * R2 + q * 8) = buf[q];
  } else {
    // Bst: thread owns row o; mask*scaling folded in.
    int o = (blockIdx.x - 8200) * 256 + tid;
    short8 buf[16];
    #pragma unroll
    for (int e = 0; e < NE; ++e) {
      float m = (mask[e] != 0) ? SCALING : 0.0f;
      #pragma unroll
      for (int rg = 0; rg < 4; ++rg) {
        float4v v = *reinterpret_cast<const float4v*>(lB + ((size_t)e * Ntot + o) * NR + rg * 4);
        ((short*)buf)[e * 16 + rg * 4 + 0] = (short)f2bf(v[0] * m);
        ((short*)buf)[e * 16 + rg * 4 + 1] = (short)f2bf(v[1] * m);
        ((short*)buf)[e * 16 + rg * 4 + 2] = (short)f2bf(v[2] * m);
        ((short*)buf)[e * 16 + rg * 4 + 3] = (short)f2bf(v[3] * m);
      }
    }
    #pragma unroll
    for (int q = 0; q < 16; ++q)
      *reinterpret_cast<short8*>(Bst + (size_t)o * R2 + q * 8) = buf[q];
  }
}

// ---------- kernel 2: W_eff via MFMA: Wb = bf16(W + Bst @ Abt^T) ----------
// 128x128 tile, 4 waves (2x2), K=128 single-shot in LDS, XOR-swizzled.
__global__ __launch_bounds__(256) void k_weff_mfma(const ushort* __restrict__ Bst, // [2048][128]
                                                   const ushort* __restrict__ Abt, // [2048][128]
                                                   const float* __restrict__ W,    // [2048][2048]
                                                   ushort* __restrict__ Wb) {      // [2048][128? no: 2048][2048]
  __shared__ __align__(128) char sA[32768];  // Bst tile: 128 rows(o) x 256B
  __shared__ __align__(128) char sB[32768];  // Abt tile: 128 rows(d) x 256B
  int bid = blockIdx.x;
  int o0 = (bid >> 4) * 128;
  int d0 = (bid & 15) * 128;
  int tid = threadIdx.x, w = tid >> 6, l = tid & 63;

  // stage: wave w covers rows w*32+j*4+(l>>4), slot l&15; linear LDS dest,
  // source col XOR'd with ((row&7)<<4)  (both-sides rule #21).
  int srow = w * 32 + (l >> 4);
  int scolb = (l & 15) * 16;
  #pragma unroll
  for (int j = 0; j < 8; ++j) {
    int row = srow + j * 4;
    int colb = scolb ^ ((row & 7) << 4);
    lds16((const char*)Bst + (size_t)(o0 + row) * 256 + colb, sA + w * 8192 + j * 1024);
    lds16((const char*)Abt + (size_t)(d0 + row) * 256 + colb, sB + w * 8192 + j * 1024);
  }
  __syncthreads();

  int wr = w >> 1, wc = w & 1;     // wave -> 64x64 out sub-tile
  int fr = l & 15;
  int fk16 = (l >> 4) * 16;
  int xm = (fr & 7) << 4;

  f32x4 acc[4][4];
  #pragma unroll
  for (int i = 0; i < 4; ++i)
    #pragma unroll
    for (int j = 0; j < 4; ++j) acc[i][j] = f32x4{0.f, 0.f, 0.f, 0.f};

  #pragma unroll
  for (int ks = 0; ks < 4; ++ks) {
    int kx = (ks * 64 + fk16) ^ xm;
    bf16x8 aF[4], bF[4];
    #pragma unroll
    for (int mi = 0; mi < 4; ++mi)
      aF[mi] = *reinterpret_cast<const bf16x8*>(sA + (wr * 64 + mi * 16 + fr) * 256 + kx);
    #pragma unroll
    for (int nj = 0; nj < 4; ++nj)
      bF[nj] = *reinterpret_cast<const bf16x8*>(sB + (wc * 64 + nj * 16 + fr) * 256 + kx);
    #pragma unroll
    for (int mi = 0; mi < 4; ++mi)
      #pragma unroll
      for (int nj = 0; nj < 4; ++nj)
        acc[mi][nj] = __builtin_amdgcn_mfma_f32_16x16x32_bf16(aF[mi], bF[nj], acc[mi][nj], 0, 0, 0);
  }

  // epilogue: Wb[row][col] = bf16(W[row][col] + acc); C/D map col=lane&15.
  int rr4 = (l >> 4) * 4;
  #pragma unroll
  for (int nj = 0; nj < 4; ++nj) {
    int col = d0 + wc * 64 + nj * 16 + fr;
    #pragma unroll
    for (int mi = 0; mi < 4; ++mi) {
      int row0 = o0 + wr * 64 + mi * 16 + rr4;
      #pragma unroll
      for (int r = 0; r < 4; ++r) {
        float v = acc[mi][nj][r] + W[(size_t)(row0 + r) * Ktot + col];
        Wb[(size_t)(row0 + r) * Ktot + col] = f2bf(v);
      }
    }
  }
}

// ---------- kernel 3: 256x256-tile 8-wave GEMM (unchanged, validated R4) ----------
__global__ __launch_bounds__(512, 2) void k_gemm256(const ushort* __restrict__ Xb,
                                                    const ushort* __restrict__ Wb,
                                                    const float* __restrict__ bias,
                                                    float* __restrict__ out) {
  constexpr int BK = 32;
  constexpr int NT = Ktot / BK;           // 64
  constexpr int NTN = Ntot / 256;         // 8
  __shared__ __align__(128) char smem[4 * 32768];   // ring: 4 x (A 16KB + B 16KB)

  int nwg = gridDim.x;                    // 256, %8==0
  int orig = blockIdx.x;
  int wg = (orig & 7) * (nwg >> 3) + (orig >> 3);
  int mBase = (wg / NTN) * 256;
  int nBase = (wg % NTN) * 256;

  int tid = threadIdx.x;
  int w = tid >> 6, l = tid & 63;
  int wr = w >> 2, wc = w & 3;            // wave -> 128x64 output sub-tile

  int rowOff = tid >> 2;
  int cbS = ((tid & 3) * 16) ^ (((tid >> 3) & 3) << 4);
  const char* xbB = (const char*)Xb;
  const char* wbB = (const char*)Wb;
  const char* src[4];
  src[0] = xbB + (size_t)(mBase +       rowOff) * (Ktot * 2) + cbS;  // A rows 0-127
  src[1] = xbB + (size_t)(mBase + 128 + rowOff) * (Ktot * 2) + cbS;  // A rows 128-255
  src[2] = wbB + (size_t)(nBase +       rowOff) * (Ktot * 2) + cbS;  // B rows 0-127
  src[3] = wbB + (size_t)(nBase + 128 + rowOff) * (Ktot * 2) + cbS;  // B rows 128-255
  int waveB = w * 1024;

  auto stage = [&](int bufn, int which, size_t kb) {
    lds16(src[which] + kb, smem + bufn * 32768 + which * 8192 + waveB);
  };

  int fr = l & 15;
  int fkb = (l >> 4) * 16;
  int kx = fkb ^ (((fr >> 1) & 3) << 4);
  int aRd = (wr * 128 + fr) * 64 + kx;            // + mi*1024
  int bRd = 16384 + (wc * 64 + fr) * 64 + kx;     // + nj*1024

  f32x4 acc[8][4];
  #pragma unroll
  for (int i = 0; i < 8; ++i)
    #pragma unroll
    for (int j = 0; j < 4; ++j) acc[i][j] = f32x4{0.f, 0.f, 0.f, 0.f};

  bf16x8 aF[4], bF[4];

  #pragma unroll
  for (int q = 0; q < 4; ++q) stage(0, q, 0);
  #pragma unroll
  for (int q = 0; q < 4; ++q) stage(1, q, 64);
  __syncthreads();

  for (int t = 0; t < NT; ++t) {
    const char* buf = smem + (t & 3) * 32768;
    const bool pref = (t + 2 < NT);
    const int bn = (t + 2) & 3;
    const size_t kb = (size_t)(t + 2) * 64;

    // ---- phase 0: quadrant mh=0 ----
    #pragma unroll
    for (int mi = 0; mi < 4; ++mi)
      aF[mi] = *reinterpret_cast<const bf16x8*>(buf + aRd + mi * 1024);
    #pragma unroll
    for (int nj = 0; nj < 4; ++nj)
      bF[nj] = *reinterpret_cast<const bf16x8*>(buf + bRd + nj * 1024);
    if (pref) { stage(bn, 0, kb); stage(bn, 1, kb); }
    __builtin_amdgcn_s_barrier();
    __builtin_amdgcn_s_setprio(1);
    #pragma unroll
    for (int mi = 0; mi < 4; ++mi)
      #pragma unroll
      for (int nj = 0; nj < 4; ++nj)
        acc[mi][nj] = __builtin_amdgcn_mfma_f32_16x16x32_bf16(aF[mi], bF[nj], acc[mi][nj], 0, 0, 0);
    __builtin_amdgcn_s_setprio(0);
    __builtin_amdgcn_s_barrier();

    // ---- phase 1: quadrant mh=1 (B frags reused) ----
    #pragma unroll
    for (int mi = 0; mi < 4; ++mi)
      aF[mi] = *reinterpret_cast<const bf16x8*>(buf + aRd + (4 + mi) * 1024);
    if (pref) { stage(bn, 2, kb); stage(bn, 3, kb); }
    __builtin_amdgcn_s_barrier();
    __builtin_amdgcn_s_setprio(1);
    #pragma unroll
    for (int mi = 0; mi < 4; ++mi)
      #pragma unroll
      for (int nj = 0; nj < 4; ++nj)
        acc[4 + mi][nj] = __builtin_amdgcn_mfma_f32_16x16x32_bf16(aF[mi], bF[nj], acc[4 + mi][nj], 0, 0, 0);
    __builtin_amdgcn_s_setprio(0);

    if (t + 2 < NT)      asm volatile("s_waitcnt vmcnt(4)" ::: "memory");
    else if (t + 1 < NT) asm volatile("s_waitcnt vmcnt(0)" ::: "memory");
    __builtin_amdgcn_s_barrier();
  }

  int rr = (l >> 4) * 4;
  #pragma unroll
  for (int nj = 0; nj < 4; ++nj) {
    int col = nBase + wc * 64 + nj * 16 + fr;
    float bb = bias[col];
    #pragma unroll
    for (int mi = 0; mi < 8; ++mi) {
      int row0 = mBase + wr * 128 + mi * 16 + rr;
      #pragma unroll
      for (int r = 0; r < 4; ++r)
        out[(size_t)(row0 + r) * Ntot + col] = acc[mi][nj][r] + bb;
    }
  }
}

extern "C" void kernel_launch(void* const* d_in, const int* in_sizes, int n_in,
                              void* d_out, int out_size, void* d_ws, size_t ws_size,
                              hipStream_t stream) {
  const float* x    = (const float*)d_in[0];
  const float* W    = (const float*)d_in[1];
  const float* bias = (const float*)d_in[2];
  const float* lA   = (const float*)d_in[3];
  const float* lB   = (const float*)d_in[4];
  const int*   mask = (const int*)d_in[5];
  float* out = (float*)d_out;

  ushort* xb  = (ushort*)d_ws;                      // [M][K]   bf16: 33.55 MB
  ushort* wb  = xb + (size_t)Mtot * Ktot;           // [N][K]   bf16:  8.39 MB
  ushort* abt = wb + (size_t)Ntot * Ktot;           // [K][128] bf16:  0.52 MB
  ushort* bst = abt + (size_t)Ktot * R2;            // [N][128] bf16:  0.52 MB

  k_prep<<<8192 + 8 + 8, 256, 0, stream>>>(x, xb, lA, lB, mask, abt, bst);
  k_weff_mfma<<<(Ntot / 128) * (Ktot / 128), 256, 0, stream>>>(bst, abt, W, wb);
  k_gemm256<<<(Mtot / 256) * (Ntot / 256), 512, 0, stream>>>(xb, wb, bias, out);
}